// Round 12
// baseline (1687.351 us; speedup 1.0000x reference)
//
#include <hip/hip_runtime.h>

#define Bn  16
#define Ln  256
#define D0n 64
#define Hn  128
#define H4n 512
#define Kn  512
#define BLn 4096   // Bn*Ln

typedef float f4 __attribute__((ext_vector_type(4)));
typedef unsigned long long u64;

__device__ __forceinline__ float sigf(float x) { return 1.0f / (1.0f + expf(-x)); }

__device__ __forceinline__ float fma4v(f4 w, f4 x, float acc) {
    acc = fmaf(w.x, x.x, acc);
    acc = fmaf(w.y, x.y, acc);
    acc = fmaf(w.z, x.z, acc);
    acc = fmaf(w.w, x.w, acc);
    return acc;
}

__device__ __forceinline__ float dotn(const f4* __restrict__ a,
                                      const f4* __restrict__ w, int n4) {
    float a0 = 0.f, a1 = 0.f, a2 = 0.f, a3 = 0.f;
    for (int i = 0; i < n4; i += 4) {
        a0 = fma4v(a[i], w[i], a0);
        a1 = fma4v(a[i + 1], w[i + 1], a1);
        a2 = fma4v(a[i + 2], w[i + 2], a2);
        a3 = fma4v(a[i + 3], w[i + 3], a3);
    }
    return (a0 + a1) + (a2 + a3);
}

// tagged-payload helpers: (tag<<32) | float bits, single 8B relaxed atomic
__device__ __forceinline__ void tag_store(u64* p, float v, unsigned tag) {
    u64 pk = ((u64)tag << 32) | (u64)__float_as_uint(v);
    __hip_atomic_store(p, pk, __ATOMIC_RELAXED, __HIP_MEMORY_SCOPE_AGENT);
}
__device__ __forceinline__ float tag_poll(u64* p, unsigned tag) {
    u64 v;
    do {
        v = __hip_atomic_load(p, __ATOMIC_RELAXED, __HIP_MEMORY_SCOPE_AGENT);
    } while ((unsigned)(v >> 32) != tag);
    return __uint_as_float((unsigned)v);
}

// ---- tiled GEMM: Y[r][c] = scale*(X[r].W[c]) + b[c]; tiles 64r x 64c -------
__global__ __launch_bounds__(256)
void k_gemm(const float* __restrict__ X, const float* __restrict__ W,
            const float* __restrict__ b, float* __restrict__ Y,
            int K, int out_dim, int do_relu, float scale) {
    __shared__ f4 wt[4160];               // 64 x (K/4+1) max = 64x65
    const int K4 = K >> 2;
    const int st = K4 + 1;
    const int lg = __ffs(K4) - 1;
    const int tid = threadIdx.x;
    const int c = tid & 63, rpart = tid >> 6;
    const f4* W4 = (const f4*)W;
    const int per = (64 * K4) >> 8;       // K/16
    for (int i = 0; i < per; ++i) {
        int idx = i * 256 + tid;
        int row = idx >> lg, col = idx & (K4 - 1);
        wt[row * st + col] = W4[(size_t)(blockIdx.x * 64 + row) * K4 + col];
    }
    __syncthreads();
    const f4* X4 = (const f4*)X;
    const float bc = b ? b[blockIdx.x * 64 + c] : 0.f;
    const f4* wrow = wt + c * st;
    for (int i = 0; i < 16; ++i) {
        int r = blockIdx.y * 64 + i * 4 + rpart;
        const f4* xr = X4 + (size_t)r * K4;
        float a0 = 0.f, a1 = 0.f, a2 = 0.f, a3 = 0.f;
        for (int k = 0; k < K4; k += 4) {
            a0 = fma4v(wrow[k],     xr[k],     a0);
            a1 = fma4v(wrow[k + 1], xr[k + 1], a1);
            a2 = fma4v(wrow[k + 2], xr[k + 2], a2);
            a3 = fma4v(wrow[k + 3], xr[k + 3], a3);
        }
        float acc = scale * ((a0 + a1) + (a2 + a3)) + bc;
        if (do_relu) acc = fmaxf(acc, 0.f);
        Y[(size_t)r * out_dim + blockIdx.x * 64 + c] = acc;
    }
}

// -------- small transpose: out[c][r] = in[r][c] --------
__global__ void k_transpose(const float* __restrict__ in, float* __restrict__ out,
                            int R, int C) {
    int idx = blockIdx.x * blockDim.x + threadIdx.x;
    if (idx >= R * C) return;
    int c = idx / R, r = idx % R;
    out[idx] = in[(size_t)r * C + c];
}

__global__ void k_zero(int* __restrict__ p, int n) {
    int i = blockIdx.x * blockDim.x + threadIdx.x;
    if (i < n) p[i] = 0;
}

// ---- Wih rearrange for BC wave-map: out[side][k][tid] = Wih[grow][half*16+k]
// tid = w*64+lane; lane = q*16 + j2*2 + half; grow = q*128 + side*64 + w*8 + j2
__global__ void k_rearrWihBC(const f4* __restrict__ in, f4* __restrict__ out) {
    int idx = blockIdx.x * blockDim.x + threadIdx.x;   // 16384
    if (idx >= 16384) return;
    int tid = idx & 511, k = (idx >> 9) & 15, side = idx >> 13;
    int w = tid >> 6, lane = tid & 63;
    int q = lane >> 4, j2 = (lane & 15) >> 1, half = lane & 1;
    int grow = q * 128 + side * 64 + w * 8 + j2;
    out[idx] = in[(size_t)grow * 32 + half * 16 + k];
}

// ---- Whh second-half rearrange for LSTM: out[dir][k][row] = Whh[row][16+k] --
__global__ void k_rearrWhhL(const f4* __restrict__ whf, const f4* __restrict__ whb,
                            f4* __restrict__ out) {
    int idx = blockIdx.x * blockDim.x + threadIdx.x;   // 16384
    if (idx >= 16384) return;
    int row = idx & 511, k = (idx >> 9) & 15, dir = idx >> 13;
    const f4* src = dir ? whb : whf;
    out[idx] = src[(size_t)row * 32 + 16 + k];
}

// ---- KQF[b][k][tid] = kq[b*256 + (tid>>1)][(tid&1)*16 + k], f4 ----
__global__ void k_rearrKQF(const f4* __restrict__ in, f4* __restrict__ out) {
    int idx = blockIdx.x * blockDim.x + threadIdx.x;   // 131072
    if (idx >= 131072) return;
    int tid = idx & 511, k = (idx >> 9) & 15, b = idx >> 13;
    out[idx] = in[((size_t)b * 256 + (tid >> 1)) * 32 + (tid & 1) * 16 + k];
}

// -------- cst[p] = scale*(bq . kp[p]) + (mask[p]==0 ? -1e9 : 0) --------
__global__ void k_cst(const float* __restrict__ kp, const float* __restrict__ bq,
                      const float* __restrict__ mask, float* __restrict__ cst) {
    int p = blockIdx.x * blockDim.x + threadIdx.x;
    if (p >= BLn) return;
    float a = dotn((const f4*)bq, (const f4*)(kp + (size_t)p * Hn), Hn >> 2);
    cst[p] = a * 0.088388347648318447f + (mask[p] == 0.f ? -1e9f : 0.f);
}

// -------- codebook squared norms --------
__global__ void k_codenorm(const float* __restrict__ emb, float* __restrict__ c2) {
    int k = blockIdx.x * blockDim.x + threadIdx.x;
    if (k >= Kn) return;
    const f4* e4 = (const f4*)(emb + (size_t)k * Hn);
    float acc = 0.f;
    for (int i = 0; i < Hn / 4; ++i) {
        f4 v = e4[i];
        acc = fmaf(v.x, v.x, acc); acc = fmaf(v.y, v.y, acc);
        acc = fmaf(v.z, v.z, acc); acc = fmaf(v.w, v.w, acc);
    }
    c2[k] = acc;
}

// -------- VQ pick: argmin over dist row (first-index ties) + gather ---------
__global__ __launch_bounds__(128)
void k_vqpick(const float* __restrict__ dist, const float* __restrict__ emb,
              float* __restrict__ zq) {
    const int p = blockIdx.x, tid = threadIdx.x;
    __shared__ int best_s;
    if (tid < 64) {
        float best = 3.0e38f; int bi = 0;
        for (int j = 0; j < 8; ++j) {
            int k = j * 64 + tid;
            float d = dist[(size_t)p * Kn + k];
            if (d < best) { best = d; bi = k; }
        }
        for (int off = 32; off > 0; off >>= 1) {
            float ov = __shfl_xor(best, off);
            int   oi = __shfl_xor(bi, off);
            if (ov < best || (ov == best && oi < bi)) { best = ov; bi = oi; }
        }
        if (tid == 0) best_s = bi;
    }
    __syncthreads();
    zq[(size_t)p * Hn + tid] = emb[(size_t)best_s * Hn + tid];
}

// -------- LSTM v3: ONE block per (batch,dir), 512 thr, 1 thread/row ---------
// Whh row: first half pinned (16 f4 = 64 VGPR), second half from LDS
// (lane-contiguous [k][512]). No exchange, no shfl, 2 barriers/step.
__global__ __launch_bounds__(512, 1)
void k_lstm3(const float* __restrict__ xWf, const float* __restrict__ xWb,
             const float* __restrict__ Whh_f, const float* __restrict__ Whh_b,
             const float* __restrict__ WhhL_g, float* __restrict__ hcat) {
    const int b   = blockIdx.x & 15;
    const int dir = blockIdx.x >> 4;
    const int tid = threadIdx.x;               // = gate row
    const float* xW  = dir ? xWb : xWf;
    const f4* Whh4   = (const f4*)(dir ? Whh_b : Whh_f);

    __shared__ __align__(16) f4 wh2_s[16 * 512];   // 128 KB second halves
    __shared__ __align__(16) float h_s[Hn];
    __shared__ float g_s[H4n];

    f4 w[16];
#pragma unroll
    for (int f = 0; f < 16; ++f) w[f] = Whh4[(size_t)tid * 32 + f];
#pragma unroll
    for (int f = 0; f < 16; ++f) asm volatile("" : "+v"(w[f]));

    const f4* WhhL4 = (const f4*)WhhL_g;
#pragma unroll
    for (int k = 0; k < 16; ++k)
        wh2_s[k * 512 + tid] = WhhL4[(size_t)dir * 8192 + k * 512 + tid];

    float c_reg = 0.f;
    if (tid < Hn) h_s[tid] = 0.f;

    const int t0 = dir ? (Ln - 1) : 0;
    float xw_v = xW[((size_t)b * Ln + t0) * H4n + tid];
    __syncthreads();

    for (int s = 0; s < Ln; ++s) {
        const int t = dir ? (Ln - 1 - s) : s;
        float xw_n = 0.f;
        if (s + 1 < Ln) {
            int tn = dir ? (Ln - 2 - s) : (s + 1);
            xw_n = xW[((size_t)b * Ln + tn) * H4n + tid];
        }
        {
            const f4* h4 = (const f4*)h_s;
            float a0 = 0.f, a1 = 0.f, a2 = 0.f, a3 = 0.f;
#pragma unroll
            for (int f = 0; f < 16; f += 4) {               // h[0:64) via regs
                a0 = fma4v(w[f],     h4[f],     a0);
                a1 = fma4v(w[f + 1], h4[f + 1], a1);
                a2 = fma4v(w[f + 2], h4[f + 2], a2);
                a3 = fma4v(w[f + 3], h4[f + 3], a3);
            }
#pragma unroll
            for (int f = 0; f < 16; f += 4) {               // h[64:128) via LDS
                a0 = fma4v(wh2_s[f * 512 + tid],       h4[16 + f],     a0);
                a1 = fma4v(wh2_s[(f + 1) * 512 + tid], h4[16 + f + 1], a1);
                a2 = fma4v(wh2_s[(f + 2) * 512 + tid], h4[16 + f + 2], a2);
                a3 = fma4v(wh2_s[(f + 3) * 512 + tid], h4[16 + f + 3], a3);
            }
            g_s[tid] = (a0 + a1) + (a2 + a3) + xw_v;
        }
        __syncthreads();
        if (tid < Hn) {
            float ig = sigf(g_s[tid]);
            float fg = sigf(g_s[Hn + tid]);
            float gg = tanhf(g_s[2 * Hn + tid]);
            float og = sigf(g_s[3 * Hn + tid]);
            c_reg = fg * c_reg + ig * gg;
            float hv = og * tanhf(c_reg);
            h_s[tid] = hv;
            hcat[((size_t)b * Ln + t) * (2 * Hn) + dir * Hn + tid] = hv;
        }
        __syncthreads();
        xw_v = xw_n;
    }
}

// -------- decoder: 2 blocks/batch x 512 thr; BC-fused; 5 barriers/step ------
// BC wave-map: lane = q*16 + j2*2 + half; wave w owns comps w*8+j2 (all 4
// quadrants in-wave) -> gates via shfl, cell + tagged exchange same phase.
// Pinned: whh 16f4 (64) + vwr 32 + bdr = 97. Wih in LDS 128KB. KQ/W1 streamed.
__global__ __launch_bounds__(512, 1)
void k_decoder(const float* __restrict__ kqF_g, const float* __restrict__ vw_g,
               const float* __restrict__ cst_g,
               const float* __restrict__ W1,  const float* __restrict__ b1_g,
               const float* __restrict__ WihBC_g, const float* __restrict__ Whh,
               const float* __restrict__ bd_g, u64* gxd,
               float* __restrict__ dec_out, float* __restrict__ attn_w) {
    const int b    = blockIdx.x & 15;
    const int side = blockIdx.x >> 4;     // b and b+16 same XCD
    const int tid  = threadIdx.x;

    __shared__ __align__(16) f4 wih_s[16 * 512];   // 128 KB, lane-contiguous
    __shared__ __align__(16) float tok_s[D0n];
    __shared__ __align__(16) float x_s[Hn];
    __shared__ __align__(16) float h_s[Hn];
    __shared__ float s_s[Ln];
    __shared__ float attn_sp[8][33];               // padded (slab-major)
    __shared__ float cst_s[Ln];
    __shared__ float b1_s[Hn];

    // BC wave-map
    const int w    = tid >> 6;
    const int lane = tid & 63;
    const int q    = lane >> 4;
    const int j2   = (lane & 15) >> 1;
    const int half = lane & 1;
    const int grow = q * 128 + side * 64 + w * 8 + j2;

    // ---- pinned: whh half-row + VW slice + bias ----
    const f4* Whh4 = (const f4*)Whh;
    f4 whh[16];
#pragma unroll
    for (int f = 0; f < 16; ++f) whh[f] = Whh4[(size_t)grow * 32 + half * 16 + f];
    float bdr = bd_g[grow];
    const int o = tid >> 3, slab = tid & 7;        // out phase map
    float vwr[32];
#pragma unroll
    for (int l = 0; l < 32; ++l)
        vwr[l] = vw_g[((size_t)b * Ln + slab * 32 + l) * D0n + o];
#pragma unroll
    for (int f = 0; f < 16; ++f) asm volatile("" : "+v"(whh[f]));
#pragma unroll
    for (int l = 0; l < 32; ++l) asm volatile("" : "+v"(vwr[l]));
    asm volatile("" : "+v"(bdr));

    // ---- stage Wih into LDS (coalesced both ends, BC layout) ----
    const f4* WihBC4 = (const f4*)WihBC_g;
#pragma unroll
    for (int k = 0; k < 16; ++k)
        wih_s[k * 512 + tid] = WihBC4[(size_t)side * 8192 + k * 512 + tid];
    if (tid < D0n) tok_s[tid] = 0.f;
    if (tid < Hn)  { h_s[tid] = 0.f; b1_s[tid] = b1_g[tid]; }
    if (tid < Ln)  cst_s[tid] = cst_g[(size_t)b * Ln + tid];
    float c_reg = 0.f;
    __syncthreads();

    u64* gx_mine = gxd + (b * 2 + side) * 128;
    u64* gx_peer = gxd + (b * 2 + (side ^ 1)) * 128;

    const int ar = tid >> 2, ap = tid & 3;         // x phase: 128 rows x 4 thr
    const f4* W1_4 = (const f4*)W1;
    const f4* kqF  = (const f4*)kqF_g + (size_t)b * 8192;
    const int dbase = (tid & 1) * 16;              // score phase h offset

    for (int t = 0; t < Ln; ++t) {
        // ---- A: x = relu(W1 @ tok + b1); W1 streamed (L2-hot) ----
        {
            const f4* t4 = (const f4*)tok_s;
            float u0 = 0.f, u1 = 0.f;
#pragma unroll
            for (int k = 0; k < 4; k += 2) {
                f4 wa  = W1_4[(size_t)ar * 16 + ap * 4 + k];
                f4 wb2 = W1_4[(size_t)ar * 16 + ap * 4 + k + 1];
                u0 = fma4v(wa,  t4[ap * 4 + k],     u0);
                u1 = fma4v(wb2, t4[ap * 4 + k + 1], u1);
            }
            float a = u0 + u1;
            a += __shfl_xor(a, 1);
            a += __shfl_xor(a, 2);
            if (ap == 0) x_s[ar] = fmaxf(a + b1_s[ar], 0.f);
        }
        __syncthreads();
        // ---- BC (fused): gates via shfl -> cell -> tagged exchange ----
        {
            const f4* x4 = (const f4*)x_s + half * 16;
            const f4* h4 = (const f4*)h_s + half * 16;
            float a0 = 0.f, a1 = 0.f, a2 = 0.f, a3 = 0.f;
#pragma unroll
            for (int f = 0; f < 16; f += 4) {
                a0 = fma4v(wih_s[f * 512 + tid],       x4[f],     a0);
                a1 = fma4v(wih_s[(f + 1) * 512 + tid], x4[f + 1], a1);
                a2 = fma4v(wih_s[(f + 2) * 512 + tid], x4[f + 2], a2);
                a3 = fma4v(wih_s[(f + 3) * 512 + tid], x4[f + 3], a3);
            }
#pragma unroll
            for (int f = 0; f < 16; f += 4) {
                a0 = fma4v(whh[f],     h4[f],     a0);
                a1 = fma4v(whh[f + 1], h4[f + 1], a1);
                a2 = fma4v(whh[f + 2], h4[f + 2], a2);
                a3 = fma4v(whh[f + 3], h4[f + 3], a3);
            }
            float g = (a0 + a1) + (a2 + a3);
            g += __shfl_xor(g, 1);          // pair halves -> full row sum
            g += bdr;                        // per-row bias (same on both halves)
            // gather i,f,g,o for comp j2 from lanes (lane&15)+16q
            float gI = __shfl(g, (lane & 15));
            float gF = __shfl(g, (lane & 15) + 16);
            float gG = __shfl(g, (lane & 15) + 32);
            float gO = __shfl(g, (lane & 15) + 48);
            if (lane < 16 && half == 0) {    // cell lanes: comp w*8+j2
                float ig = sigf(gI), fg = sigf(gF);
                float gg = tanhf(gG), og = sigf(gO);
                c_reg = fg * c_reg + ig * gg;
                float hv = og * tanhf(c_reg);
                int idx = w * 8 + j2;
                h_s[side * 64 + idx] = hv;
                tag_store(&gx_mine[(t & 1) * 64 + idx], hv, (unsigned)(t + 1));
            }
            if (lane < 16 && half == 1) {    // poll lanes: peer comp w*8+j2
                int idx = w * 8 + j2;
                h_s[(side ^ 1) * 64 + idx] =
                    tag_poll(&gx_peer[(t & 1) * 64 + idx], (unsigned)(t + 1));
            }
        }
        __syncthreads();
        // ---- D: scores; KQ streamed coalesced from L2 (L2-hot) ----
        {
            const f4* h4 = (const f4*)h_s;
            float a0 = 0.f, a1 = 0.f;
#pragma unroll
            for (int k = 0; k < 16; k += 2) {
                f4 q0 = kqF[(size_t)k * 512 + tid];
                f4 q1 = kqF[(size_t)(k + 1) * 512 + tid];
                a0 = fma4v(q0, h4[dbase + k],     a0);
                a1 = fma4v(q1, h4[dbase + k + 1], a1);
            }
            float a = a0 + a1;
            a += __shfl_xor(a, 1);
            if ((tid & 1) == 0) s_s[tid >> 1] = a + cst_s[tid >> 1];
        }
        __syncthreads();
        // ---- E: softmax (wave 0); side 0 writes attn_w ----
        if (tid < 64) {
            float v0 = s_s[tid],       v1 = s_s[tid + 64];
            float v2 = s_s[tid + 128], v3 = s_s[tid + 192];
            float m = fmaxf(fmaxf(v0, v1), fmaxf(v2, v3));
#pragma unroll
            for (int o2 = 32; o2 > 0; o2 >>= 1) m = fmaxf(m, __shfl_xor(m, o2));
            float e0 = expf(v0 - m), e1 = expf(v1 - m);
            float e2 = expf(v2 - m), e3 = expf(v3 - m);
            float ss = (e0 + e1) + (e2 + e3);
#pragma unroll
            for (int o2 = 32; o2 > 0; o2 >>= 1) ss += __shfl_xor(ss, o2);
            float inv = 1.f / ss;
            e0 *= inv; e1 *= inv; e2 *= inv; e3 *= inv;
            attn_sp[tid >> 5][tid & 31] = e0;
            attn_sp[(tid + 64) >> 5][tid & 31] = e1;
            attn_sp[(tid + 128) >> 5][tid & 31] = e2;
            attn_sp[(tid + 192) >> 5][tid & 31] = e3;
            if (side == 0) {
                float* aw = attn_w + ((size_t)b * Ln + t) * Ln;
                aw[tid] = e0; aw[tid + 64] = e1;
                aw[tid + 128] = e2; aw[tid + 192] = e3;
            }
        }
        __syncthreads();
        // ---- F: out[o] = sum_l attn[l]*VW'[l][o]; 64 o x 8 slabs ----
        {
            const float* as = attn_sp[slab];
            float g0 = 0.f, g1 = 0.f, g2 = 0.f, g3 = 0.f;
#pragma unroll
            for (int l = 0; l < 32; l += 4) {
                g0 = fmaf(as[l],     vwr[l],     g0);
                g1 = fmaf(as[l + 1], vwr[l + 1], g1);
                g2 = fmaf(as[l + 2], vwr[l + 2], g2);
                g3 = fmaf(as[l + 3], vwr[l + 3], g3);
            }
            float a = (g0 + g1) + (g2 + g3);
            a += __shfl_xor(a, 1);
            a += __shfl_xor(a, 2);
            a += __shfl_xor(a, 4);
            if (slab == 0) {
                tok_s[o] = a;
                if (side == 1) dec_out[((size_t)b * Ln + t) * D0n + o] = a;
            }
        }
        __syncthreads();
    }
}

extern "C" void kernel_launch(void* const* d_in, const int* in_sizes, int n_in,
                              void* d_out, int out_size, void* d_ws, size_t ws_size,
                              hipStream_t stream) {
    const float* inputs     = (const float*)d_in[0];
    const float* in_mask    = (const float*)d_in[2];
    const float* enc_lin1_W = (const float*)d_in[3];
    const float* enc_lin1_b = (const float*)d_in[4];
    const float* enc_Wih_f  = (const float*)d_in[5];
    const float* enc_Whh_f  = (const float*)d_in[6];
    const float* enc_b_f    = (const float*)d_in[7];
    const float* enc_Wih_b  = (const float*)d_in[8];
    const float* enc_Whh_b  = (const float*)d_in[9];
    const float* enc_b_b    = (const float*)d_in[10];
    const float* enc_lin2_W = (const float*)d_in[11];
    const float* enc_lin2_b = (const float*)d_in[12];
    const float* vq_emb     = (const float*)d_in[13];
    const float* dec_lin1_W = (const float*)d_in[14];
    const float* dec_lin1_b = (const float*)d_in[15];
    const float* dec_Wih    = (const float*)d_in[16];
    const float* dec_Whh    = (const float*)d_in[17];
    const float* dec_b      = (const float*)d_in[18];
    const float* attn_Wq    = (const float*)d_in[19];
    const float* attn_bq    = (const float*)d_in[20];
    const float* attn_Wk    = (const float*)d_in[21];
    const float* attn_bk    = (const float*)d_in[22];
    const float* attn_Wv    = (const float*)d_in[23];
    const float* attn_bv    = (const float*)d_in[24];
    const float* dec_lin2_W = (const float*)d_in[25];
    const float* dec_lin2_b = (const float*)d_in[26];

    float* out     = (float*)d_out;
    float* dec_out = out;                       // 16*256*64   = 262144
    float* attn_w  = out + 262144;              // 16*256*256  = 1048576
    float* ze      = out + 1310720;             // 16*256*128  = 524288
    float* zq      = out + 1835008;             // 16*256*128  = 524288

    float* ws    = (float*)d_ws;
    float* enc_x = ws;                          // 524288
    float* xWf   = enc_x + 524288;              // 2097152
    float* xWb   = xWf + 2097152;               // 2097152
    float* hcat  = xWb + 2097152;               // 1048576
    float* kp    = hcat + 1048576;              // 524288
    float* vp    = kp + 524288;                 // 524288
    float* c2    = vp + 524288;                 // 512
    u64*   gxd   = (u64*)(c2 + 512);            // 32*128 u64 = 4096 u64
    // aliases into dead regions:
    float* WqT   = enc_x;                       // 16384 (enc_x dead after xW GEMMs)
    float* WihBC = enc_x + 16384;               // 65536 floats = 16384 f4
    float* WhhL  = enc_x + 16384 + 65536;       // 65536 floats = 16384 f4
    float* dist  = xWf;                         // 2097152 (dead after vqpick)
    float* KQF   = xWf;                         // 131072 f4 = 524288 floats
    float* kq    = xWb;                         // 524288  (xWb dead post-LSTM)
    float* vw    = xWb + 524288;                // 262144
    float* cst   = xWb + 786432;                // 4096

    dim3 blk(256);
    // ---- encoder front ----
    k_gemm<<<dim3(2, 64), blk, 0, stream>>>(inputs, enc_lin1_W, enc_lin1_b, enc_x, D0n, Hn, 1, 1.f);
    k_gemm<<<dim3(8, 64), blk, 0, stream>>>(enc_x, enc_Wih_f, enc_b_f, xWf, Hn, H4n, 0, 1.f);
    k_gemm<<<dim3(8, 64), blk, 0, stream>>>(enc_x, enc_Wih_b, enc_b_b, xWb, Hn, H4n, 0, 1.f);
    k_transpose<<<64, 256, 0, stream>>>(attn_Wq, WqT, Hn, Hn);
    k_rearrWihBC<<<64, 256, 0, stream>>>((const f4*)dec_Wih, (f4*)WihBC);
    k_rearrWhhL<<<64, 256, 0, stream>>>((const f4*)enc_Whh_f, (const f4*)enc_Whh_b, (f4*)WhhL);
    k_zero<<<32, 256, 0, stream>>>((int*)gxd, 8192);
    // ---- BiLSTM: 32 blocks = 16b x 2dir, single-block (no exchange) ----
    k_lstm3<<<32, 512, 0, stream>>>(xWf, xWb, enc_Whh_f, enc_Whh_b, WhhL, hcat);
    k_gemm<<<dim3(2, 64), blk, 0, stream>>>(hcat, enc_lin2_W, enc_lin2_b, ze, 2 * Hn, Hn, 0, 1.f);
    // ---- VQ ----
    k_codenorm<<<2, 256, 0, stream>>>(vq_emb, c2);
    k_gemm<<<dim3(8, 64), blk, 0, stream>>>(ze, vq_emb, c2, dist, Hn, Kn, 0, -2.f);
    k_vqpick<<<BLn, 128, 0, stream>>>(dist, vq_emb, zq);
    // ---- attention precomputes (dec_in == zq) ----
    k_gemm<<<dim3(2, 64), blk, 0, stream>>>(zq, attn_Wk, attn_bk, kp, Hn, Hn, 0, 1.f);
    k_gemm<<<dim3(2, 64), blk, 0, stream>>>(zq, attn_Wv, attn_bv, vp, Hn, Hn, 0, 1.f);
    k_gemm<<<dim3(2, 64), blk, 0, stream>>>(kp, WqT, nullptr, kq, Hn, Hn, 0, 0.088388347648318447f);
    k_rearrKQF<<<512, 256, 0, stream>>>((const f4*)kq, (f4*)KQF);
    k_gemm<<<dim3(1, 64), blk, 0, stream>>>(vp, dec_lin2_W, dec_lin2_b, vw, Hn, D0n, 0, 1.f);
    k_cst<<<Bn, 256, 0, stream>>>(kp, attn_bq, in_mask, cst);
    // ---- decoder: 32 blocks = 16 batches x 2 sides, 512 thr ----
    k_decoder<<<32, 512, 0, stream>>>(KQF, vw, cst,
                                      dec_lin1_W, dec_lin1_b,
                                      WihBC, dec_Whh, dec_b, gxd,
                                      dec_out, attn_w);
}

// Round 13
// 1633.492 us; speedup vs baseline: 1.0330x; 1.0330x over previous
//
#include <hip/hip_runtime.h>

#define Bn  16
#define Ln  256
#define D0n 64
#define Hn  128
#define H4n 512
#define Kn  512
#define BLn 4096   // Bn*Ln

typedef float f4 __attribute__((ext_vector_type(4)));
typedef unsigned long long u64;

__device__ __forceinline__ float sigf(float x) { return 1.0f / (1.0f + expf(-x)); }

__device__ __forceinline__ float fma4v(f4 w, f4 x, float acc) {
    acc = fmaf(w.x, x.x, acc);
    acc = fmaf(w.y, x.y, acc);
    acc = fmaf(w.z, x.z, acc);
    acc = fmaf(w.w, x.w, acc);
    return acc;
}

__device__ __forceinline__ float dotn(const f4* __restrict__ a,
                                      const f4* __restrict__ w, int n4) {
    float a0 = 0.f, a1 = 0.f, a2 = 0.f, a3 = 0.f;
    for (int i = 0; i < n4; i += 4) {
        a0 = fma4v(a[i], w[i], a0);
        a1 = fma4v(a[i + 1], w[i + 1], a1);
        a2 = fma4v(a[i + 2], w[i + 2], a2);
        a3 = fma4v(a[i + 3], w[i + 3], a3);
    }
    return (a0 + a1) + (a2 + a3);
}

// tagged-payload helpers: (tag<<32) | float bits, single 8B relaxed atomic
__device__ __forceinline__ void tag_store(u64* p, float v, unsigned tag) {
    u64 pk = ((u64)tag << 32) | (u64)__float_as_uint(v);
    __hip_atomic_store(p, pk, __ATOMIC_RELAXED, __HIP_MEMORY_SCOPE_AGENT);
}
__device__ __forceinline__ float tag_poll(u64* p, unsigned tag) {
    u64 v;
    do {
        v = __hip_atomic_load(p, __ATOMIC_RELAXED, __HIP_MEMORY_SCOPE_AGENT);
    } while ((unsigned)(v >> 32) != tag);
    return __uint_as_float((unsigned)v);
}

// ---- tiled GEMM: Y[r][c] = scale*(X[r].W[c]) + b[c]; tiles 64r x 64c -------
__global__ __launch_bounds__(256)
void k_gemm(const float* __restrict__ X, const float* __restrict__ W,
            const float* __restrict__ b, float* __restrict__ Y,
            int K, int out_dim, int do_relu, float scale) {
    __shared__ f4 wt[4160];               // 64 x (K/4+1) max = 64x65
    const int K4 = K >> 2;
    const int st = K4 + 1;
    const int lg = __ffs(K4) - 1;
    const int tid = threadIdx.x;
    const int c = tid & 63, rpart = tid >> 6;
    const f4* W4 = (const f4*)W;
    const int per = (64 * K4) >> 8;       // K/16
    for (int i = 0; i < per; ++i) {
        int idx = i * 256 + tid;
        int row = idx >> lg, col = idx & (K4 - 1);
        wt[row * st + col] = W4[(size_t)(blockIdx.x * 64 + row) * K4 + col];
    }
    __syncthreads();
    const f4* X4 = (const f4*)X;
    const float bc = b ? b[blockIdx.x * 64 + c] : 0.f;
    const f4* wrow = wt + c * st;
    for (int i = 0; i < 16; ++i) {
        int r = blockIdx.y * 64 + i * 4 + rpart;
        const f4* xr = X4 + (size_t)r * K4;
        float a0 = 0.f, a1 = 0.f, a2 = 0.f, a3 = 0.f;
        for (int k = 0; k < K4; k += 4) {
            a0 = fma4v(wrow[k],     xr[k],     a0);
            a1 = fma4v(wrow[k + 1], xr[k + 1], a1);
            a2 = fma4v(wrow[k + 2], xr[k + 2], a2);
            a3 = fma4v(wrow[k + 3], xr[k + 3], a3);
        }
        float acc = scale * ((a0 + a1) + (a2 + a3)) + bc;
        if (do_relu) acc = fmaxf(acc, 0.f);
        Y[(size_t)r * out_dim + blockIdx.x * 64 + c] = acc;
    }
}

// ---- fused prep: WqT transpose | WihL2 rearr | WhhL rearr | zero tags ------
__global__ void k_prep(const float* __restrict__ attn_Wq, float* __restrict__ WqT,
                       const f4* __restrict__ dec_Wih, f4* __restrict__ WihL,
                       const f4* __restrict__ whf, const f4* __restrict__ whb,
                       f4* __restrict__ WhhL, int* __restrict__ zbuf) {
    const int blk = blockIdx.x, tid = threadIdx.x;
    if (blk < 64) {                        // WqT[c][r] = Wq[r][c], 128x128
        int idx = blk * 256 + tid;
        int c = idx >> 7, r = idx & 127;
        WqT[idx] = attn_Wq[(size_t)r * Hn + c];
    } else if (blk < 128) {                // WihL[k*1024 + side*512 + t]
        int idx = (blk - 64) * 256 + tid;  // 16384
        int t = idx & 511, side = (idx >> 9) & 1, k = idx >> 10;
        int rl = t >> 1;
        int grow = (rl >> 6) * 128 + side * 64 + (rl & 63);
        WihL[idx] = dec_Wih[(size_t)grow * 32 + (t & 1) * 16 + k];
    } else if (blk < 192) {                // WhhL[dir][k][row] = Whh[row][16+k]
        int idx = (blk - 128) * 256 + tid; // 16384
        int row = idx & 511, k = (idx >> 9) & 15, dir = idx >> 13;
        const f4* src = dir ? whb : whf;
        WhhL[idx] = src[(size_t)row * 32 + 16 + k];
    } else {                               // zero 8192 ints of tag space
        int idx = (blk - 192) * 256 + tid;
        if (idx < 8192) zbuf[idx] = 0;
    }
}

// ---- KQF[b][k][tid] = kq[b*256 + (tid>>1)][(tid&1)*16 + k], f4 ----
__global__ void k_rearrKQF(const f4* __restrict__ in, f4* __restrict__ out) {
    int idx = blockIdx.x * blockDim.x + threadIdx.x;   // 131072
    if (idx >= 131072) return;
    int tid = idx & 511, k = (idx >> 9) & 15, b = idx >> 13;
    out[idx] = in[((size_t)b * 256 + (tid >> 1)) * 32 + (tid & 1) * 16 + k];
}

// -------- cst[p] = scale*(bq . kp[p]) + (mask[p]==0 ? -1e9 : 0) --------
__global__ void k_cst(const float* __restrict__ kp, const float* __restrict__ bq,
                      const float* __restrict__ mask, float* __restrict__ cst) {
    int p = blockIdx.x * blockDim.x + threadIdx.x;
    if (p >= BLn) return;
    float a = dotn((const f4*)bq, (const f4*)(kp + (size_t)p * Hn), Hn >> 2);
    cst[p] = a * 0.088388347648318447f + (mask[p] == 0.f ? -1e9f : 0.f);
}

// -------- codebook squared norms --------
__global__ void k_codenorm(const float* __restrict__ emb, float* __restrict__ c2) {
    int k = blockIdx.x * blockDim.x + threadIdx.x;
    if (k >= Kn) return;
    const f4* e4 = (const f4*)(emb + (size_t)k * Hn);
    float acc = 0.f;
    for (int i = 0; i < Hn / 4; ++i) {
        f4 v = e4[i];
        acc = fmaf(v.x, v.x, acc); acc = fmaf(v.y, v.y, acc);
        acc = fmaf(v.z, v.z, acc); acc = fmaf(v.w, v.w, acc);
    }
    c2[k] = acc;
}

// -------- VQ pick: argmin over dist row (first-index ties) + gather ---------
__global__ __launch_bounds__(128)
void k_vqpick(const float* __restrict__ dist, const float* __restrict__ emb,
              float* __restrict__ zq) {
    const int p = blockIdx.x, tid = threadIdx.x;
    __shared__ int best_s;
    if (tid < 64) {
        float best = 3.0e38f; int bi = 0;
        for (int j = 0; j < 8; ++j) {
            int k = j * 64 + tid;
            float d = dist[(size_t)p * Kn + k];
            if (d < best) { best = d; bi = k; }
        }
        for (int off = 32; off > 0; off >>= 1) {
            float ov = __shfl_xor(best, off);
            int   oi = __shfl_xor(bi, off);
            if (ov < best || (ov == best && oi < bi)) { best = ov; bi = oi; }
        }
        if (tid == 0) best_s = bi;
    }
    __syncthreads();
    zq[(size_t)p * Hn + tid] = emb[(size_t)best_s * Hn + tid];
}

// -------- LSTM v3: ONE block per (batch,dir), 512 thr, 1 thread/row ---------
__global__ __launch_bounds__(512, 1)
void k_lstm3(const float* __restrict__ xWf, const float* __restrict__ xWb,
             const float* __restrict__ Whh_f, const float* __restrict__ Whh_b,
             const float* __restrict__ WhhL_g, float* __restrict__ hcat) {
    const int b   = blockIdx.x & 15;
    const int dir = blockIdx.x >> 4;
    const int tid = threadIdx.x;               // = gate row
    const float* xW  = dir ? xWb : xWf;
    const f4* Whh4   = (const f4*)(dir ? Whh_b : Whh_f);

    __shared__ __align__(16) f4 wh2_s[16 * 512];   // 128 KB second halves
    __shared__ __align__(16) float h_s[Hn];
    __shared__ float g_s[H4n];

    f4 w[16];
#pragma unroll
    for (int f = 0; f < 16; ++f) w[f] = Whh4[(size_t)tid * 32 + f];
#pragma unroll
    for (int f = 0; f < 16; ++f) asm volatile("" : "+v"(w[f]));

    const f4* WhhL4 = (const f4*)WhhL_g;
#pragma unroll
    for (int k = 0; k < 16; ++k)
        wh2_s[k * 512 + tid] = WhhL4[(size_t)dir * 8192 + k * 512 + tid];

    float c_reg = 0.f;
    if (tid < Hn) h_s[tid] = 0.f;

    const int t0 = dir ? (Ln - 1) : 0;
    float xw_v = xW[((size_t)b * Ln + t0) * H4n + tid];
    __syncthreads();

    for (int s = 0; s < Ln; ++s) {
        const int t = dir ? (Ln - 1 - s) : s;
        float xw_n = 0.f;
        if (s + 1 < Ln) {
            int tn = dir ? (Ln - 2 - s) : (s + 1);
            xw_n = xW[((size_t)b * Ln + tn) * H4n + tid];
        }
        {
            const f4* h4 = (const f4*)h_s;
            float a0 = 0.f, a1 = 0.f, a2 = 0.f, a3 = 0.f;
#pragma unroll
            for (int f = 0; f < 16; f += 4) {               // h[0:64) via regs
                a0 = fma4v(w[f],     h4[f],     a0);
                a1 = fma4v(w[f + 1], h4[f + 1], a1);
                a2 = fma4v(w[f + 2], h4[f + 2], a2);
                a3 = fma4v(w[f + 3], h4[f + 3], a3);
            }
#pragma unroll
            for (int f = 0; f < 16; f += 4) {               // h[64:128) via LDS
                a0 = fma4v(wh2_s[f * 512 + tid],       h4[16 + f],     a0);
                a1 = fma4v(wh2_s[(f + 1) * 512 + tid], h4[16 + f + 1], a1);
                a2 = fma4v(wh2_s[(f + 2) * 512 + tid], h4[16 + f + 2], a2);
                a3 = fma4v(wh2_s[(f + 3) * 512 + tid], h4[16 + f + 3], a3);
            }
            g_s[tid] = (a0 + a1) + (a2 + a3) + xw_v;
        }
        __syncthreads();
        if (tid < Hn) {
            float ig = sigf(g_s[tid]);
            float fg = sigf(g_s[Hn + tid]);
            float gg = tanhf(g_s[2 * Hn + tid]);
            float og = sigf(g_s[3 * Hn + tid]);
            c_reg = fg * c_reg + ig * gg;
            float hv = og * tanhf(c_reg);
            h_s[tid] = hv;
            hcat[((size_t)b * Ln + t) * (2 * Hn) + dir * Hn + tid] = hv;
        }
        __syncthreads();
        xw_v = xw_n;
    }
}

// -------- decoder: 2 blocks/batch x 512 thr; R11 structure + EF-merge -------
// 5 barriers/step: A | B | C(cell+tagged exch) | D | EF(per-wave softmax+out).
// Pinned: whh 16f4 (64) + vwr 32 + bdr = 97. Wih in LDS 128KB. KQ/W1 streamed.
__global__ __launch_bounds__(512, 1)
void k_decoder(const float* __restrict__ kqF_g, const float* __restrict__ vw_g,
               const float* __restrict__ cst_g,
               const float* __restrict__ W1,  const float* __restrict__ b1_g,
               const float* __restrict__ WihL_g, const float* __restrict__ Whh,
               const float* __restrict__ bd_g, u64* gxd,
               float* __restrict__ dec_out, float* __restrict__ attn_w) {
    const int b    = blockIdx.x & 15;
    const int side = blockIdx.x >> 4;     // b and b+16 same XCD
    const int tid  = threadIdx.x;

    __shared__ __align__(16) f4 wih_s[16 * 512];   // 128 KB, lane-contiguous
    __shared__ __align__(16) float tok_s[D0n];
    __shared__ __align__(16) float x_s[Hn];
    __shared__ __align__(16) float h_s[Hn];
    __shared__ float g_loc[256];
    __shared__ float s_s[Ln];
    __shared__ float attn8[8][8][33];              // per-wave private copies
    __shared__ float cst_s[Ln];
    __shared__ float b1_s[Hn];

    const int rl = tid >> 1, ghalf = tid & 1;      // gates: 256 rows x 2 thr
    const int grow = (rl >> 6) * 128 + side * 64 + (rl & 63);

    // ---- pinned: whh half-row + VW slice + bias ----
    const f4* Whh4 = (const f4*)Whh;
    f4 whh[16];
#pragma unroll
    for (int f = 0; f < 16; ++f) whh[f] = Whh4[(size_t)grow * 32 + ghalf * 16 + f];
    float bdr = bd_g[grow];
    const int o = tid >> 3, slab = tid & 7;        // out phase map
    float vwr[32];
#pragma unroll
    for (int l = 0; l < 32; ++l)
        vwr[l] = vw_g[((size_t)b * Ln + slab * 32 + l) * D0n + o];
#pragma unroll
    for (int f = 0; f < 16; ++f) asm volatile("" : "+v"(whh[f]));
#pragma unroll
    for (int l = 0; l < 32; ++l) asm volatile("" : "+v"(vwr[l]));
    asm volatile("" : "+v"(bdr));

    // ---- stage Wih into LDS (coalesced both ends) ----
    const f4* WihL4 = (const f4*)WihL_g;
#pragma unroll
    for (int k = 0; k < 16; ++k)
        wih_s[k * 512 + tid] = WihL4[(size_t)k * 1024 + side * 512 + tid];
    if (tid < D0n) tok_s[tid] = 0.f;
    if (tid < Hn)  { h_s[tid] = 0.f; b1_s[tid] = b1_g[tid]; }
    if (tid < Ln)  cst_s[tid] = cst_g[(size_t)b * Ln + tid];
    float c_reg = 0.f;
    __syncthreads();

    u64* gx_mine = gxd + (b * 2 + side) * 128;
    u64* gx_peer = gxd + (b * 2 + (side ^ 1)) * 128;

    const int ar = tid >> 2, ap = tid & 3;         // x phase: 128 rows x 4 thr
    const f4* W1_4 = (const f4*)W1;
    const f4* kqF  = (const f4*)kqF_g + (size_t)b * 8192;
    const int dbase = (tid & 1) * 16;              // score phase h offset
    const int wv = tid >> 6, lane = tid & 63;

    for (int t = 0; t < Ln; ++t) {
        // ---- A: x = relu(W1 @ tok + b1); W1 streamed (L2-hot) ----
        {
            const f4* t4 = (const f4*)tok_s;
            float u0 = 0.f, u1 = 0.f;
#pragma unroll
            for (int k = 0; k < 4; k += 2) {
                f4 wa  = W1_4[(size_t)ar * 16 + ap * 4 + k];
                f4 wb2 = W1_4[(size_t)ar * 16 + ap * 4 + k + 1];
                u0 = fma4v(wa,  t4[ap * 4 + k],     u0);
                u1 = fma4v(wb2, t4[ap * 4 + k + 1], u1);
            }
            float a = u0 + u1;
            a += __shfl_xor(a, 1);
            a += __shfl_xor(a, 2);
            if (ap == 0) x_s[ar] = fmaxf(a + b1_s[ar], 0.f);
        }
        __syncthreads();
        // ---- B: gates; Wih from LDS (lane-contig), Whh pinned ----
        {
            const f4* x4 = (const f4*)x_s + ghalf * 16;
            const f4* h4 = (const f4*)h_s + ghalf * 16;
            float a0 = 0.f, a1 = 0.f, a2 = 0.f, a3 = 0.f;
#pragma unroll
            for (int f = 0; f < 16; f += 4) {
                a0 = fma4v(wih_s[f * 512 + tid],       x4[f],     a0);
                a1 = fma4v(wih_s[(f + 1) * 512 + tid], x4[f + 1], a1);
                a2 = fma4v(wih_s[(f + 2) * 512 + tid], x4[f + 2], a2);
                a3 = fma4v(wih_s[(f + 3) * 512 + tid], x4[f + 3], a3);
            }
#pragma unroll
            for (int f = 0; f < 16; f += 4) {
                a0 = fma4v(whh[f],     h4[f],     a0);
                a1 = fma4v(whh[f + 1], h4[f + 1], a1);
                a2 = fma4v(whh[f + 2], h4[f + 2], a2);
                a3 = fma4v(whh[f + 3], h4[f + 3], a3);
            }
            float a = (a0 + a1) + (a2 + a3);
            a += __shfl_xor(a, 1);
            if (ghalf == 0) g_loc[rl] = a + bdr;
        }
        __syncthreads();
        // ---- C: cell (own 64) + tagged publish + poll peer (fused) ----
        if (tid < 64) {
            float ig = sigf(g_loc[tid]);
            float fg = sigf(g_loc[64 + tid]);
            float gg = tanhf(g_loc[128 + tid]);
            float og = sigf(g_loc[192 + tid]);
            c_reg = fg * c_reg + ig * gg;
            float hv = og * tanhf(c_reg);
            h_s[side * 64 + tid] = hv;
            tag_store(&gx_mine[(t & 1) * 64 + tid], hv, (unsigned)(t + 1));
            h_s[(side ^ 1) * 64 + tid] =
                tag_poll(&gx_peer[(t & 1) * 64 + tid], (unsigned)(t + 1));
        }
        __syncthreads();
        // ---- D: scores; KQ streamed coalesced from L2 (L2-hot) ----
        {
            const f4* h4 = (const f4*)h_s;
            float a0 = 0.f, a1 = 0.f;
#pragma unroll
            for (int k = 0; k < 16; k += 2) {
                f4 q0 = kqF[(size_t)k * 512 + tid];
                f4 q1 = kqF[(size_t)(k + 1) * 512 + tid];
                a0 = fma4v(q0, h4[dbase + k],     a0);
                a1 = fma4v(q1, h4[dbase + k + 1], a1);
            }
            float a = a0 + a1;
            a += __shfl_xor(a, 1);
            if ((tid & 1) == 0) s_s[tid >> 1] = a + cst_s[tid >> 1];
        }
        __syncthreads();
        // ---- EF: per-wave redundant softmax + out; no intra barrier ----
        {
            float v0 = s_s[lane],       v1 = s_s[lane + 64];
            float v2 = s_s[lane + 128], v3 = s_s[lane + 192];
            float m = fmaxf(fmaxf(v0, v1), fmaxf(v2, v3));
#pragma unroll
            for (int o2 = 32; o2 > 0; o2 >>= 1) m = fmaxf(m, __shfl_xor(m, o2));
            float e0 = expf(v0 - m), e1 = expf(v1 - m);
            float e2 = expf(v2 - m), e3 = expf(v3 - m);
            float ss = (e0 + e1) + (e2 + e3);
#pragma unroll
            for (int o2 = 32; o2 > 0; o2 >>= 1) ss += __shfl_xor(ss, o2);
            float inv = 1.f / ss;
            e0 *= inv; e1 *= inv; e2 *= inv; e3 *= inv;
            attn8[wv][lane >> 5][lane & 31] = e0;
            attn8[wv][(lane + 64) >> 5][lane & 31] = e1;
            attn8[wv][(lane + 128) >> 5][lane & 31] = e2;
            attn8[wv][(lane + 192) >> 5][lane & 31] = e3;
            if (side == 0 && wv == 0) {
                float* aw = attn_w + ((size_t)b * Ln + t) * Ln;
                aw[lane] = e0; aw[lane + 64] = e1;
                aw[lane + 128] = e2; aw[lane + 192] = e3;
            }
            // order own-wave LDS writes before reads (same wave, no barrier)
            asm volatile("s_waitcnt lgkmcnt(0)" ::: "memory");
            const float* as = attn8[wv][slab];
            float g0 = 0.f, g1 = 0.f, g2 = 0.f, g3 = 0.f;
#pragma unroll
            for (int l = 0; l < 32; l += 4) {
                g0 = fmaf(as[l],     vwr[l],     g0);
                g1 = fmaf(as[l + 1], vwr[l + 1], g1);
                g2 = fmaf(as[l + 2], vwr[l + 2], g2);
                g3 = fmaf(as[l + 3], vwr[l + 3], g3);
            }
            float a = (g0 + g1) + (g2 + g3);
            a += __shfl_xor(a, 1);
            a += __shfl_xor(a, 2);
            a += __shfl_xor(a, 4);
            if (slab == 0) {
                tok_s[o] = a;
                if (side == 1) dec_out[((size_t)b * Ln + t) * D0n + o] = a;
            }
        }
        __syncthreads();
    }
}

extern "C" void kernel_launch(void* const* d_in, const int* in_sizes, int n_in,
                              void* d_out, int out_size, void* d_ws, size_t ws_size,
                              hipStream_t stream) {
    const float* inputs     = (const float*)d_in[0];
    const float* in_mask    = (const float*)d_in[2];
    const float* enc_lin1_W = (const float*)d_in[3];
    const float* enc_lin1_b = (const float*)d_in[4];
    const float* enc_Wih_f  = (const float*)d_in[5];
    const float* enc_Whh_f  = (const float*)d_in[6];
    const float* enc_b_f    = (const float*)d_in[7];
    const float* enc_Wih_b  = (const float*)d_in[8];
    const float* enc_Whh_b  = (const float*)d_in[9];
    const float* enc_b_b    = (const float*)d_in[10];
    const float* enc_lin2_W = (const float*)d_in[11];
    const float* enc_lin2_b = (const float*)d_in[12];
    const float* vq_emb     = (const float*)d_in[13];
    const float* dec_lin1_W = (const float*)d_in[14];
    const float* dec_lin1_b = (const float*)d_in[15];
    const float* dec_Wih    = (const float*)d_in[16];
    const float* dec_Whh    = (const float*)d_in[17];
    const float* dec_b      = (const float*)d_in[18];
    const float* attn_Wq    = (const float*)d_in[19];
    const float* attn_bq    = (const float*)d_in[20];
    const float* attn_Wk    = (const float*)d_in[21];
    const float* attn_bk    = (const float*)d_in[22];
    const float* attn_Wv    = (const float*)d_in[23];
    const float* attn_bv    = (const float*)d_in[24];
    const float* dec_lin2_W = (const float*)d_in[25];
    const float* dec_lin2_b = (const float*)d_in[26];

    float* out     = (float*)d_out;
    float* dec_out = out;                       // 16*256*64   = 262144
    float* attn_w  = out + 262144;              // 16*256*256  = 1048576
    float* ze      = out + 1310720;             // 16*256*128  = 524288
    float* zq      = out + 1835008;             // 16*256*128  = 524288

    float* ws    = (float*)d_ws;
    float* enc_x = ws;                          // 524288
    float* xWf   = enc_x + 524288;              // 2097152
    float* xWb   = xWf + 2097152;               // 2097152
    float* hcat  = xWb + 2097152;               // 1048576
    float* kp    = hcat + 1048576;              // 524288
    float* vp    = kp + 524288;                 // 524288
    float* c2    = vp + 524288;                 // 512
    u64*   gxd   = (u64*)(c2 + 512);            // 32*128 u64 = 4096 u64
    // aliases into dead regions:
    float* WqT   = enc_x;                       // 16384 (enc_x dead after xW GEMMs)
    float* WihL  = enc_x + 16384;               // 65536 floats = 16384 f4
    float* WhhL  = enc_x + 16384 + 65536;       // 65536 floats = 16384 f4
    float* dist  = xWf;                         // 2097152 (dead after vqpick)
    float* KQF   = xWf;                         // 131072 f4 = 524288 floats
    float* kq    = xWb;                         // 524288  (xWb dead post-LSTM)
    float* vw    = xWb + 524288;                // 262144
    float* cst   = xWb + 786432;                // 4096

    dim3 blk(256);
    // ---- encoder front ----
    k_gemm<<<dim3(2, 64), blk, 0, stream>>>(inputs, enc_lin1_W, enc_lin1_b, enc_x, D0n, Hn, 1, 1.f);
    k_gemm<<<dim3(8, 64), blk, 0, stream>>>(enc_x, enc_Wih_f, enc_b_f, xWf, Hn, H4n, 0, 1.f);
    k_gemm<<<dim3(8, 64), blk, 0, stream>>>(enc_x, enc_Wih_b, enc_b_b, xWb, Hn, H4n, 0, 1.f);
    // ---- fused prep: WqT | WihL | WhhL | zero tags ----
    k_prep<<<224, 256, 0, stream>>>(attn_Wq, WqT, (const f4*)dec_Wih, (f4*)WihL,
                                    (const f4*)enc_Whh_f, (const f4*)enc_Whh_b,
                                    (f4*)WhhL, (int*)gxd);
    // ---- BiLSTM: 32 blocks = 16b x 2dir, single-block (no exchange) ----
    k_lstm3<<<32, 512, 0, stream>>>(xWf, xWb, enc_Whh_f, enc_Whh_b, WhhL, hcat);
    k_gemm<<<dim3(2, 64), blk, 0, stream>>>(hcat, enc_lin2_W, enc_lin2_b, ze, 2 * Hn, Hn, 0, 1.f);
    // ---- VQ ----
    k_codenorm<<<2, 256, 0, stream>>>(vq_emb, c2);
    k_gemm<<<dim3(8, 64), blk, 0, stream>>>(ze, vq_emb, c2, dist, Hn, Kn, 0, -2.f);
    k_vqpick<<<BLn, 128, 0, stream>>>(dist, vq_emb, zq);
    // ---- attention precomputes (dec_in == zq) ----
    k_gemm<<<dim3(2, 64), blk, 0, stream>>>(zq, attn_Wk, attn_bk, kp, Hn, Hn, 0, 1.f);
    k_gemm<<<dim3(2, 64), blk, 0, stream>>>(zq, attn_Wv, attn_bv, vp, Hn, Hn, 0, 1.f);
    k_gemm<<<dim3(2, 64), blk, 0, stream>>>(kp, WqT, nullptr, kq, Hn, Hn, 0, 0.088388347648318447f);
    k_rearrKQF<<<512, 256, 0, stream>>>((const f4*)kq, (f4*)KQF);
    k_gemm<<<dim3(1, 64), blk, 0, stream>>>(vp, dec_lin2_W, dec_lin2_b, vw, Hn, D0n, 0, 1.f);
    k_cst<<<Bn, 256, 0, stream>>>(kp, attn_bq, in_mask, cst);
    // ---- decoder: 32 blocks = 16 batches x 2 sides, 512 thr ----
    k_decoder<<<32, 512, 0, stream>>>(KQF, vw, cst,
                                      dec_lin1_W, dec_lin1_b,
                                      WihL, dec_Whh, dec_b, gxd,
                                      dec_out, attn_w);
}